// Round 1
// baseline (2632.185 us; speedup 1.0000x reference)
//
#include <hip/hip_runtime.h>
#include <math.h>

#define NSPLIT 4096
#define NVQ    12288
#define NTOK   16384
#define CH     256
#define NH     8
#define DHD    32
#define NL     4
#define PW     256
#define HIDN   1024
#define DVQ    32
#define VQG    4
#define VQS    256

// ---------------- mask dtype detection (bool may arrive as i32/u8/bf16/f32) -----------
__global__ void k_detect(const unsigned short* __restrict__ u16, int* __restrict__ mode) {
    __shared__ int c_even, c_odd, c_0100;
    if (threadIdx.x == 0) { c_even = 0; c_odd = 0; c_0100 = 0; }
    __syncthreads();
    int le = 0, lo = 0, l01 = 0;
    for (int i = threadIdx.x; i < 8192; i += blockDim.x) {   // first 16384 bytes only (safe for all widths)
        unsigned short v = u16[i];
        if (v == 0x3F80u) { if (i & 1) lo++; else le++; }
        if (v == 0x0100u) l01++;
    }
    atomicAdd(&c_even, le); atomicAdd(&c_odd, lo); atomicAdd(&c_0100, l01);
    __syncthreads();
    if (threadIdx.x == 0) {
        int m;
        if      (c_even > 500) m = 2;   // bf16 (0x3F80 at even u16 slots)
        else if (c_odd  > 500) m = 3;   // f32  (0x3F80 only at odd u16 slots)
        else if (c_0100 > 500) m = 1;   // u8/bool (byte pair 00,01)
        else                   m = 0;   // int32
        *mode = m;
    }
}

__global__ void k_norm_mask(const void* __restrict__ raw, const int* __restrict__ mode,
                            int* __restrict__ mi) {
    int i = blockIdx.x * blockDim.x + threadIdx.x;
    if (i >= NTOK) return;
    int m = *mode, v;
    if      (m == 0) v = ((const int*)raw)[i] != 0;
    else if (m == 1) v = ((const unsigned char*)raw)[i] != 0;
    else if (m == 2) v = ((const unsigned short*)raw)[i] != 0;
    else             v = ((const unsigned int*)raw)[i] != 0;
    mi[i] = v;
}

// ---------------- embedding: [split_emb[split] ; zq@vq_proj+b], masked -> class cond ----
__global__ void k_embed(const int* __restrict__ split, const float* __restrict__ zq,
                        const int* __restrict__ category, const int* __restrict__ batch_id,
                        const int* __restrict__ mask_i,
                        const float* __restrict__ split_emb, const float* __restrict__ class_emb,
                        const float* __restrict__ vq_proj_w, const float* __restrict__ vq_proj_b,
                        float* __restrict__ x) {
    int idx = blockIdx.x * 256 + threadIdx.x;
    int i = idx >> 8, c = idx & 255;
    float v;
    if (mask_i[i]) {
        v = class_emb[category[batch_id[i]] * CH + c];
    } else if (i < NSPLIT) {
        v = split_emb[split[i] * CH + c];
    } else {
        const float* z = zq + (size_t)(i - NSPLIT) * DVQ;
        float acc = vq_proj_b[c];
#pragma unroll
        for (int k = 0; k < DVQ; k++) acc += z[k] * vq_proj_w[k * CH + c];
        v = acc;
    }
    x[idx] = v;
}

// ---------------- depth2batch gather + sinusoidal pos emb ------------------------------
__global__ void k_gather_pos(const float* __restrict__ x, const int* __restrict__ d2b,
                             float* __restrict__ xb) {
    int idx = blockIdx.x * 256 + threadIdx.x;
    int j = idx >> 8, c = idx & 255;
    const float kneg = -0.07195578415606394f;  // -ln(10000)/128
    float pe;
    float jf = (float)j;
    if (c < 128) { float f = expf(c * kneg);          pe = sinf(jf * f); }
    else         { float f = expf((c - 128) * kneg);  pe = cosf(jf * f); }
    xb[idx] = x[(size_t)d2b[j] * CH + c] + pe;
}

// ---------------- layernorm (row = block of 256) ---------------------------------------
__global__ void k_layernorm(const float* __restrict__ in, const float* __restrict__ s,
                            const float* __restrict__ b, float* __restrict__ out) {
    int row = blockIdx.x, c = threadIdx.x;
    float v = in[(size_t)row * CH + c];
    __shared__ float r1[256], r2[256];
    r1[c] = v; r2[c] = v * v;
    __syncthreads();
    for (int off = 128; off > 0; off >>= 1) {
        if (c < off) { r1[c] += r1[c + off]; r2[c] += r2[c + off]; }
        __syncthreads();
    }
    float mean = r1[0] * (1.0f / CH);
    float var  = r2[0] * (1.0f / CH) - mean * mean;
    out[(size_t)row * CH + c] = (v - mean) * rsqrtf(var + 1e-5f) * s[c] + b[c];
}

// ---------------- generic tiled f32 GEMM: out = act(A@W + bias) [+ res] ----------------
template <bool GELU, bool RES>
__global__ __launch_bounds__(256) void k_gemm(const float* __restrict__ A, const float* __restrict__ W,
                                              const float* __restrict__ bias, const float* __restrict__ res,
                                              float* __restrict__ out, int M, int N, int K) {
    const int BM = 64, BN = 64, BK = 16;
    __shared__ float As[BK][BM];
    __shared__ float Bs[BK][BN];
    int tid = threadIdx.x;
    int bm = blockIdx.y * BM, bn = blockIdx.x * BN;
    int tr = tid >> 4, tc = tid & 15;
    int la_m = tid >> 2, la_k = (tid & 3) * 4;
    int lb_k = tid >> 4, lb_n = (tid & 15) * 4;
    float acc[4][4] = {};
    for (int k0 = 0; k0 < K; k0 += BK) {
        float4 av = *(const float4*)(A + (size_t)(bm + la_m) * K + k0 + la_k);
        As[la_k + 0][la_m] = av.x; As[la_k + 1][la_m] = av.y;
        As[la_k + 2][la_m] = av.z; As[la_k + 3][la_m] = av.w;
        float4 bv = *(const float4*)(W + (size_t)(k0 + lb_k) * N + bn + lb_n);
        *(float4*)&Bs[lb_k][lb_n] = bv;
        __syncthreads();
#pragma unroll
        for (int k = 0; k < BK; k++) {
            float4 aq = *(const float4*)&As[k][tr * 4];
            float4 bq = *(const float4*)&Bs[k][tc * 4];
            float a[4] = {aq.x, aq.y, aq.z, aq.w};
            float b2[4] = {bq.x, bq.y, bq.z, bq.w};
#pragma unroll
            for (int i = 0; i < 4; i++)
#pragma unroll
                for (int j = 0; j < 4; j++) acc[i][j] += a[i] * b2[j];
        }
        __syncthreads();
    }
#pragma unroll
    for (int i = 0; i < 4; i++) {
        int m = bm + tr * 4 + i;
#pragma unroll
        for (int j = 0; j < 4; j++) {
            int n = bn + tc * 4 + j;
            float v = acc[i][j] + bias[n];
            if (GELU) {
                float t = tanhf(0.7978845608028654f * (v + 0.044715f * v * v * v));
                v = 0.5f * v * (1.0f + t);
            }
            size_t oi = (size_t)m * N + n;
            if (RES) v += res[oi];
            out[oi] = v;
        }
    }
}

// ---------------- fused dilated-window attention (one block per window,head) -----------
__global__ __launch_bounds__(256) void k_attn(const float* __restrict__ qkv, float* __restrict__ o,
                                              int dil) {
    __shared__ float k_lds[PW][DHD];
    __shared__ float v_lds[PW][DHD];
    int w = blockIdx.x, h = blockIdx.y;
    int p = threadIdx.x;
    int g = w / dil, j = w % dil;
    int t = g * (PW * dil) + p * dil + j;
    const float* base = qkv + (size_t)t * (3 * CH);
    float q[DHD];
#pragma unroll
    for (int c = 0; c < DHD; c += 4) {
        float4 qv = *(const float4*)(base + h * DHD + c);
        q[c] = qv.x; q[c + 1] = qv.y; q[c + 2] = qv.z; q[c + 3] = qv.w;
        *(float4*)&k_lds[p][c] = *(const float4*)(base + CH + h * DHD + c);
        *(float4*)&v_lds[p][c] = *(const float4*)(base + 2 * CH + h * DHD + c);
    }
    __syncthreads();
    const float scale = 0.17677669529663687f;  // 1/sqrt(32)
    float m = -1e30f, l = 0.f;
    float oacc[DHD] = {};
    for (int jj = 0; jj < PW; jj++) {
        float s = 0.f;
#pragma unroll
        for (int c = 0; c < DHD; c++) s += q[c] * k_lds[jj][c];
        s *= scale;
        float mnew = fmaxf(m, s);
        float f = __expf(m - mnew);
        float pv = __expf(s - mnew);
        l = l * f + pv;
#pragma unroll
        for (int c = 0; c < DHD; c++) oacc[c] = oacc[c] * f + pv * v_lds[jj][c];
        m = mnew;
    }
    float inv = 1.0f / l;
    float* ob = o + (size_t)t * CH + h * DHD;
#pragma unroll
    for (int c = 0; c < DHD; c += 4) {
        float4 v4 = {oacc[c] * inv, oacc[c + 1] * inv, oacc[c + 2] * inv, oacc[c + 3] * inv};
        *(float4*)(ob + c) = v4;
    }
}

// ---------------- batch2depth scatter (inverse permutation) ----------------------------
__global__ void k_scatter(const float* __restrict__ xb, const int* __restrict__ d2b,
                          float* __restrict__ x) {
    int j = blockIdx.x, c = threadIdx.x;
    x[(size_t)d2b[j] * CH + c] = xb[(size_t)j * CH + c];
}

// ---------------- split head + masked CE ----------------------------------------------
__global__ void k_split_loss(const float* __restrict__ xln, const int* __restrict__ split,
                             const int* __restrict__ mask_i, const float* __restrict__ sw,
                             const float* __restrict__ sb, float* __restrict__ cnt) {
    int i = blockIdx.x, c = threadIdx.x;
    float v = xln[(size_t)i * CH + c];
    __shared__ float r0[256], r1[256];
    r0[c] = v * sw[2 * c + 0];
    r1[c] = v * sw[2 * c + 1];
    __syncthreads();
    for (int off = 128; off > 0; off >>= 1) {
        if (c < off) { r0[c] += r0[c + off]; r1[c] += r1[c + off]; }
        __syncthreads();
    }
    if (c == 0) {
        float l0 = r0[0] + sb[0], l1 = r1[0] + sb[1];
        float mx = fmaxf(l0, l1);
        float lse = mx + logf(__expf(l0 - mx) + __expf(l1 - mx));
        float ce = lse - (split[i] ? l1 : l0);
        float ms = (float)mask_i[i];
        atomicAdd(&cnt[0], ce * ms);
        atomicAdd(&cnt[1], ms);
    }
}

// ---------------- vq head grouped CE (logits pre-computed by GEMM) ---------------------
__global__ void k_vq_loss(const float* __restrict__ vl, const int* __restrict__ targets,
                          const int* __restrict__ mask_i, float* __restrict__ cnt) {
    int i = blockIdx.x, c = threadIdx.x;
    const float* row = vl + (size_t)i * (VQG * VQS);
    __shared__ float red[256];
    float ce_sum = 0.f;  // thread 0 only
    for (int g = 0; g < VQG; g++) {
        float v = row[g * VQS + c];
        red[c] = v; __syncthreads();
        for (int off = 128; off > 0; off >>= 1) {
            if (c < off) red[c] = fmaxf(red[c], red[c + off]);
            __syncthreads();
        }
        float mx = red[0]; __syncthreads();
        red[c] = __expf(v - mx); __syncthreads();
        for (int off = 128; off > 0; off >>= 1) {
            if (c < off) red[c] += red[c + off];
            __syncthreads();
        }
        if (c == 0) {
            float lse = mx + logf(red[0]);
            ce_sum += lse - row[g * VQS + targets[i * VQG + g]];
        }
        __syncthreads();
    }
    if (c == 0) {
        float mv = (float)mask_i[NSPLIT + i];
        atomicAdd(&cnt[2], ce_sum * (1.0f / VQG) * mv);
        atomicAdd(&cnt[3], mv);
    }
}

__global__ void k_final(const float* __restrict__ cnt, float* __restrict__ out) {
    out[0] = cnt[0] / fmaxf(cnt[1], 1.0f);
    out[1] = cnt[2] / fmaxf(cnt[3], 1.0f);
}

// ======================================================================================
extern "C" void kernel_launch(void* const* d_in, const int* in_sizes, int n_in,
                              void* d_out, int out_size, void* d_ws, size_t ws_size,
                              hipStream_t stream) {
    const int*   split      = (const int*)d_in[0];
    const float* zq         = (const float*)d_in[1];
    const int*   targets_vq = (const int*)d_in[2];
    const int*   category   = (const int*)d_in[3];
    const int*   batch_id   = (const int*)d_in[4];
    const void*  mask_raw   = d_in[5];
    const int*   d2b        = (const int*)d_in[6];
    const float* split_emb  = (const float*)d_in[7];
    const float* class_emb  = (const float*)d_in[8];
    const float* vq_proj_w  = (const float*)d_in[9];
    const float* vq_proj_b  = (const float*)d_in[10];
    const float* ln1_s      = (const float*)d_in[11];
    const float* ln1_b      = (const float*)d_in[12];
    const float* qkv_w      = (const float*)d_in[13];
    const float* qkv_b      = (const float*)d_in[14];
    const float* attn_w     = (const float*)d_in[15];
    const float* attn_b     = (const float*)d_in[16];
    const float* ln2_s      = (const float*)d_in[17];
    const float* ln2_b      = (const float*)d_in[18];
    const float* fc1_w      = (const float*)d_in[19];
    const float* fc1_b      = (const float*)d_in[20];
    const float* fc2_w      = (const float*)d_in[21];
    const float* fc2_b      = (const float*)d_in[22];
    const float* lnx_s      = (const float*)d_in[23];
    const float* lnx_b      = (const float*)d_in[24];
    const float* sw         = (const float*)d_in[25];
    const float* sb         = (const float*)d_in[26];
    const float* vq_w       = (const float*)d_in[27];
    const float* vq_b       = (const float*)d_in[28];

    char* ws = (char*)d_ws;
    float* cnt    = (float*)(ws + 0);       // 4 f32 accumulators
    int*   mode   = (int*)(ws + 64);
    int*   mask_i = (int*)(ws + 1024);      // NTOK ints
    float* x      = (float*)(ws + (1 << 17));
    float* xb     = x  + (size_t)NTOK * CH;
    float* h      = xb + (size_t)NTOK * CH;
    float* big    = h  + (size_t)NTOK * CH;  // max(qkv 48MB, h1 64MB, vq-logits 48MB)
    float* o      = x;                       // alias: x dead during blocks

    hipMemsetAsync(cnt, 0, 16, stream);
    k_detect<<<1, 256, 0, stream>>>((const unsigned short*)mask_raw, mode);
    k_norm_mask<<<NTOK / 256, 256, 0, stream>>>(mask_raw, mode, mask_i);
    k_embed<<<NTOK, 256, 0, stream>>>(split, zq, category, batch_id, mask_i,
                                      split_emb, class_emb, vq_proj_w, vq_proj_b, x);
    k_gather_pos<<<NTOK, 256, 0, stream>>>(x, d2b, xb);

    for (int l = 0; l < NL; l++) {
        int d = (l & 1) ? 2 : 1;
        k_layernorm<<<NTOK, 256, 0, stream>>>(xb, ln1_s + l * CH, ln1_b + l * CH, h);
        dim3 g1(768 / 64, NTOK / 64);
        k_gemm<false, false><<<g1, 256, 0, stream>>>(h, qkv_w + (size_t)l * CH * 768,
                                                     qkv_b + l * 768, nullptr, big, NTOK, 768, CH);
        dim3 ga(NTOK / PW, NH);
        k_attn<<<ga, 256, 0, stream>>>(big, o, d);
        dim3 g2(CH / 64, NTOK / 64);
        k_gemm<false, true><<<g2, 256, 0, stream>>>(o, attn_w + (size_t)l * CH * CH,
                                                    attn_b + l * CH, xb, xb, NTOK, CH, CH);
        k_layernorm<<<NTOK, 256, 0, stream>>>(xb, ln2_s + l * CH, ln2_b + l * CH, h);
        dim3 g3(HIDN / 64, NTOK / 64);
        k_gemm<true, false><<<g3, 256, 0, stream>>>(h, fc1_w + (size_t)l * CH * HIDN,
                                                    fc1_b + l * HIDN, nullptr, big, NTOK, HIDN, CH);
        dim3 g4(CH / 64, NTOK / 64);
        k_gemm<false, true><<<g4, 256, 0, stream>>>(big, fc2_w + (size_t)l * HIDN * CH,
                                                    fc2_b + l * CH, xb, xb, NTOK, CH, HIDN);
    }

    k_scatter<<<NTOK, 256, 0, stream>>>(xb, d2b, x);
    k_layernorm<<<NTOK, 256, 0, stream>>>(x, lnx_s, lnx_b, h);
    k_split_loss<<<NSPLIT, 256, 0, stream>>>(h, split, mask_i, sw, sb, cnt);
    dim3 g5(1024 / 64, NVQ / 64);
    k_gemm<false, false><<<g5, 256, 0, stream>>>(h + (size_t)NSPLIT * CH, vq_w, vq_b,
                                                 nullptr, big, NVQ, 1024, CH);
    k_vq_loss<<<NVQ, 256, 0, stream>>>(big, targets_vq, mask_i, cnt);
    k_final<<<1, 1, 0, stream>>>(cnt, (float*)d_out);
}

// Round 2
// 919.244 us; speedup vs baseline: 2.8634x; 2.8634x over previous
//
#include <hip/hip_runtime.h>
#include <hip/hip_bf16.h>
#include <math.h>

#define NSPLIT 4096
#define NVQ    12288
#define NTOK   16384
#define CH     256
#define NH     8
#define DHD    32
#define NL     4
#define PW     256
#define HIDN   1024
#define DVQ    32
#define VQG    4
#define VQS    256

typedef __attribute__((ext_vector_type(8))) short bf16x8;
typedef __attribute__((ext_vector_type(4))) float f32x4;

typedef const __attribute__((address_space(1))) void* gas_ptr;
typedef __attribute__((address_space(3))) void* las_ptr;
#define GLD16(g, s) __builtin_amdgcn_global_load_lds((gas_ptr)(g), (las_ptr)(s), 16, 0, 0)

// ---------------- mask dtype detection (bool may arrive as i32/u8/bf16/f32) -----------
__global__ void k_detect(const unsigned short* __restrict__ u16, int* __restrict__ mode) {
    __shared__ int c_even, c_odd, c_0100;
    if (threadIdx.x == 0) { c_even = 0; c_odd = 0; c_0100 = 0; }
    __syncthreads();
    int le = 0, lo = 0, l01 = 0;
    for (int i = threadIdx.x; i < 8192; i += blockDim.x) {
        unsigned short v = u16[i];
        if (v == 0x3F80u) { if (i & 1) lo++; else le++; }
        if (v == 0x0100u) l01++;
    }
    atomicAdd(&c_even, le); atomicAdd(&c_odd, lo); atomicAdd(&c_0100, l01);
    __syncthreads();
    if (threadIdx.x == 0) {
        int m;
        if      (c_even > 500) m = 2;
        else if (c_odd  > 500) m = 3;
        else if (c_0100 > 500) m = 1;
        else                   m = 0;
        *mode = m;
    }
}

__global__ void k_norm_mask(const void* __restrict__ raw, const int* __restrict__ mode,
                            int* __restrict__ mi) {
    int i = blockIdx.x * blockDim.x + threadIdx.x;
    if (i >= NTOK) return;
    int m = *mode, v;
    if      (m == 0) v = ((const int*)raw)[i] != 0;
    else if (m == 1) v = ((const unsigned char*)raw)[i] != 0;
    else if (m == 2) v = ((const unsigned short*)raw)[i] != 0;
    else             v = ((const unsigned int*)raw)[i] != 0;
    mi[i] = v;
}

// ---------------- weight transpose + bf16 convert: W[K][N] -> Wt[N][K] -----------------
__global__ void k_wt(const float* __restrict__ W, __hip_bfloat16* __restrict__ Wt,
                     int K, int N) {
    W  += (size_t)blockIdx.z * K * N;
    Wt += (size_t)blockIdx.z * K * N;
    __shared__ float t[64][65];
    int bn = blockIdx.x * 64, bk = blockIdx.y * 64;
    int tid = threadIdx.x;
#pragma unroll
    for (int it = 0; it < 16; ++it) {
        int idx = it * 256 + tid; int r = idx >> 6, c = idx & 63;
        t[r][c] = W[(size_t)(bk + r) * N + bn + c];
    }
    __syncthreads();
#pragma unroll
    for (int it = 0; it < 16; ++it) {
        int idx = it * 256 + tid; int r = idx >> 6, c = idx & 63;
        Wt[(size_t)(bn + r) * K + bk + c] = __float2bfloat16(t[c][r]);
    }
}

// ---------------- embedding -----------------------------------------------------------
__global__ void k_embed(const int* __restrict__ split, const float* __restrict__ zq,
                        const int* __restrict__ category, const int* __restrict__ batch_id,
                        const int* __restrict__ mask_i,
                        const float* __restrict__ split_emb, const float* __restrict__ class_emb,
                        const float* __restrict__ vq_proj_w, const float* __restrict__ vq_proj_b,
                        float* __restrict__ x) {
    int idx = blockIdx.x * 256 + threadIdx.x;
    int i = idx >> 8, c = idx & 255;
    float v;
    if (mask_i[i]) {
        v = class_emb[category[batch_id[i]] * CH + c];
    } else if (i < NSPLIT) {
        v = split_emb[split[i] * CH + c];
    } else {
        const float* z = zq + (size_t)(i - NSPLIT) * DVQ;
        float acc = vq_proj_b[c];
#pragma unroll
        for (int k = 0; k < DVQ; k++) acc += z[k] * vq_proj_w[k * CH + c];
        v = acc;
    }
    x[idx] = v;
}

// ---------------- depth2batch gather + sinusoidal pos emb ------------------------------
__global__ void k_gather_pos(const float* __restrict__ x, const int* __restrict__ d2b,
                             float* __restrict__ xb) {
    int idx = blockIdx.x * 256 + threadIdx.x;
    int j = idx >> 8, c = idx & 255;
    const float kneg = -0.07195578415606394f;  // -ln(10000)/128
    float pe;
    float jf = (float)j;
    if (c < 128) { float f = expf(c * kneg);          pe = sinf(jf * f); }
    else         { float f = expf((c - 128) * kneg);  pe = cosf(jf * f); }
    xb[idx] = x[(size_t)d2b[j] * CH + c] + pe;
}

// ---------------- layernorm: wave per row, bf16 out ------------------------------------
__global__ void k_layernorm(const float* __restrict__ in, const float* __restrict__ s,
                            const float* __restrict__ b, __hip_bfloat16* __restrict__ out) {
    int row = blockIdx.x * 4 + (threadIdx.x >> 6);
    int l = threadIdx.x & 63;
    const float* ip = in + (size_t)row * CH;
    float4 v = *(const float4*)(ip + l * 4);
    float sum = v.x + v.y + v.z + v.w;
    float sq  = v.x * v.x + v.y * v.y + v.z * v.z + v.w * v.w;
#pragma unroll
    for (int o = 32; o; o >>= 1) { sum += __shfl_xor(sum, o); sq += __shfl_xor(sq, o); }
    float mean = sum * (1.0f / CH);
    float var  = sq * (1.0f / CH) - mean * mean;
    float rs = rsqrtf(var + 1e-5f);
    float4 sv = *(const float4*)(s + l * 4);
    float4 bv = *(const float4*)(b + l * 4);
    __hip_bfloat16 h0 = __float2bfloat16((v.x - mean) * rs * sv.x + bv.x);
    __hip_bfloat16 h1 = __float2bfloat16((v.y - mean) * rs * sv.y + bv.y);
    __hip_bfloat16 h2 = __float2bfloat16((v.z - mean) * rs * sv.z + bv.z);
    __hip_bfloat16 h3 = __float2bfloat16((v.w - mean) * rs * sv.w + bv.w);
    ushort4 pk = { *(unsigned short*)&h0, *(unsigned short*)&h1,
                   *(unsigned short*)&h2, *(unsigned short*)&h3 };
    *(ushort4*)((unsigned short*)out + (size_t)row * CH + l * 4) = pk;
}

// ---------------- MFMA bf16 GEMM: out = act(A @ Bt^T + bias) [+res] --------------------
template <int GELU, int RES, int OBF>
__global__ __launch_bounds__(256, 2) void k_mm(
    const short* __restrict__ A, const short* __restrict__ Bt,
    const float* __restrict__ bias, const float* __restrict__ res,
    float* __restrict__ outF, __hip_bfloat16* __restrict__ outB,
    int M, int N, int K) {
    __shared__ short As[128 * 32];
    __shared__ short Bs[128 * 32];
    const int tid = threadIdx.x;
    const int w = tid >> 6, l = tid & 63;
    const int bm = blockIdx.y * 128, bn = blockIdx.x * 128;
    const int wr = w >> 1, wc = w & 1;
    const int q = l >> 4, rA = l & 15;
    const int srow = w * 16 + (l >> 2);
    const int sx = ((l & 3) ^ ((l >> 2) & 3)) * 8;
    const int fx = (q ^ (rA & 3)) * 8;

    const short* gA0 = A + (size_t)(bm + srow) * K + sx;
    const short* gA1 = A + (size_t)(bm + srow + 64) * K + sx;
    const short* gB0 = Bt + (size_t)(bn + srow) * K + sx;
    const short* gB1 = Bt + (size_t)(bn + srow + 64) * K + sx;
    short* lA0 = As + w * 16 * 32;
    short* lA1 = As + (64 + w * 16) * 32;
    short* lB0 = Bs + w * 16 * 32;
    short* lB1 = Bs + (64 + w * 16) * 32;

    f32x4 acc[4][4] = {};

    for (int k0 = 0; k0 < K; k0 += 32) {
        GLD16(gA0 + k0, lA0);
        GLD16(gA1 + k0, lA1);
        GLD16(gB0 + k0, lB0);
        GLD16(gB1 + k0, lB1);
        __syncthreads();
        bf16x8 a[4], b[4];
#pragma unroll
        for (int m = 0; m < 4; m++)
            a[m] = *(const bf16x8*)(As + (wr * 64 + m * 16 + rA) * 32 + fx);
#pragma unroll
        for (int n = 0; n < 4; n++)
            b[n] = *(const bf16x8*)(Bs + (wc * 64 + n * 16 + rA) * 32 + fx);
#pragma unroll
        for (int m = 0; m < 4; m++)
#pragma unroll
            for (int n = 0; n < 4; n++)
                acc[m][n] = __builtin_amdgcn_mfma_f32_16x16x32_bf16(a[m], b[n], acc[m][n], 0, 0, 0);
        __syncthreads();
    }

#pragma unroll
    for (int m = 0; m < 4; m++) {
        int row0 = bm + wr * 64 + m * 16 + q * 4;
#pragma unroll
        for (int n = 0; n < 4; n++) {
            int col = bn + wc * 64 + n * 16 + rA;
            float bv = bias[col];
#pragma unroll
            for (int r2 = 0; r2 < 4; r2++) {
                int row = row0 + r2;
                float v = acc[m][n][r2] + bv;
                if (GELU) {
                    float t = tanhf(0.7978845608028654f * (v + 0.044715f * v * v * v));
                    v = 0.5f * v * (1.0f + t);
                }
                size_t oi = (size_t)row * N + col;
                if (RES) v += res[oi];
                if (OBF) outB[oi] = __float2bfloat16(v);
                else     outF[oi] = v;
            }
        }
    }
}

// ---------------- fused dilated-window attention (f32 in, bf16 out) --------------------
__global__ __launch_bounds__(256) void k_attn(const float* __restrict__ qkv,
                                              __hip_bfloat16* __restrict__ o, int dil) {
    __shared__ float k_lds[PW][DHD];
    __shared__ float v_lds[PW][DHD];
    int w = blockIdx.x, h = blockIdx.y;
    int p = threadIdx.x;
    int g = w / dil, j = w % dil;
    int t = g * (PW * dil) + p * dil + j;
    const float* base = qkv + (size_t)t * (3 * CH);
    float q[DHD];
#pragma unroll
    for (int c = 0; c < DHD; c += 4) {
        float4 qv = *(const float4*)(base + h * DHD + c);
        q[c] = qv.x; q[c + 1] = qv.y; q[c + 2] = qv.z; q[c + 3] = qv.w;
        *(float4*)&k_lds[p][c] = *(const float4*)(base + CH + h * DHD + c);
        *(float4*)&v_lds[p][c] = *(const float4*)(base + 2 * CH + h * DHD + c);
    }
    __syncthreads();
    const float scale = 0.17677669529663687f;
    float m = -1e30f, lsum = 0.f;
    float oacc[DHD] = {};
    for (int jj = 0; jj < PW; jj++) {
        float s = 0.f;
#pragma unroll
        for (int c = 0; c < DHD; c++) s += q[c] * k_lds[jj][c];
        s *= scale;
        float mnew = fmaxf(m, s);
        float f = __expf(m - mnew);
        float pv = __expf(s - mnew);
        lsum = lsum * f + pv;
#pragma unroll
        for (int c = 0; c < DHD; c++) oacc[c] = oacc[c] * f + pv * v_lds[jj][c];
        m = mnew;
    }
    float inv = 1.0f / lsum;
    __hip_bfloat16* ob = o + (size_t)t * CH + h * DHD;
#pragma unroll
    for (int c = 0; c < DHD; c++) ob[c] = __float2bfloat16(oacc[c] * inv);
}

// ---------------- batch2depth scatter --------------------------------------------------
__global__ void k_scatter(const float* __restrict__ xb, const int* __restrict__ d2b,
                          float* __restrict__ x) {
    int j = blockIdx.x, c = threadIdx.x;
    x[(size_t)d2b[j] * CH + c] = xb[(size_t)j * CH + c];
}

// ---------------- split head + masked CE (wave per token, partials) --------------------
__global__ void k_split(const __hip_bfloat16* __restrict__ xln, const int* __restrict__ split,
                        const int* __restrict__ mask_i, const float* __restrict__ sw,
                        const float* __restrict__ sb, float* __restrict__ sce,
                        float* __restrict__ smv) {
    int tok = blockIdx.x * 4 + (threadIdx.x >> 6);
    int l = threadIdx.x & 63;
    float a0 = 0.f, a1 = 0.f;
#pragma unroll
    for (int jj = 0; jj < 4; jj++) {
        int c = l + 64 * jj;
        float v = __bfloat162float(xln[(size_t)tok * CH + c]);
        a0 += v * sw[2 * c + 0];
        a1 += v * sw[2 * c + 1];
    }
#pragma unroll
    for (int o = 32; o; o >>= 1) { a0 += __shfl_xor(a0, o); a1 += __shfl_xor(a1, o); }
    if (l == 0) {
        float l0 = a0 + sb[0], l1 = a1 + sb[1];
        float mx = fmaxf(l0, l1);
        float lse = mx + logf(__expf(l0 - mx) + __expf(l1 - mx));
        float ce = lse - (split[tok] ? l1 : l0);
        float ms = (float)mask_i[tok];
        sce[tok] = ce * ms;
        smv[tok] = ms;
    }
}

// ---------------- vq grouped CE (wave per group, partials) -----------------------------
__global__ void k_vq_loss(const float* __restrict__ vl, const int* __restrict__ targets,
                          const int* __restrict__ mask_i, float* __restrict__ vce,
                          float* __restrict__ vmv) {
    int i = blockIdx.x;
    int wv = threadIdx.x >> 6;
    int l = threadIdx.x & 63;
    const float* row = vl + (size_t)i * (VQG * VQS) + wv * VQS;
    float4 v = *(const float4*)(row + l * 4);
    float mx = fmaxf(fmaxf(v.x, v.y), fmaxf(v.z, v.w));
#pragma unroll
    for (int o = 32; o; o >>= 1) mx = fmaxf(mx, __shfl_xor(mx, o));
    float s = __expf(v.x - mx) + __expf(v.y - mx) + __expf(v.z - mx) + __expf(v.w - mx);
#pragma unroll
    for (int o = 32; o; o >>= 1) s += __shfl_xor(s, o);
    __shared__ float ce[VQG];
    if (l == 0) ce[wv] = (mx + logf(s)) - row[targets[i * VQG + wv]];
    __syncthreads();
    if (threadIdx.x == 0) {
        float mv = (float)mask_i[NSPLIT + i];
        vce[i] = (ce[0] + ce[1] + ce[2] + ce[3]) * 0.25f * mv;
        vmv[i] = mv;
    }
}

// ---------------- final reduction ------------------------------------------------------
__global__ void k_reduce(const float* __restrict__ sce, const float* __restrict__ smv,
                         const float* __restrict__ vce, const float* __restrict__ vmv,
                         float* __restrict__ out) {
    int tid = threadIdx.x;
    float s1 = 0, s2 = 0, s3 = 0, s4 = 0;
    for (int i = tid; i < NSPLIT; i += 256) { s1 += sce[i]; s2 += smv[i]; }
    for (int i = tid; i < NVQ; i += 256)    { s3 += vce[i]; s4 += vmv[i]; }
    __shared__ float r1[256], r2[256], r3[256], r4[256];
    r1[tid] = s1; r2[tid] = s2; r3[tid] = s3; r4[tid] = s4;
    __syncthreads();
    for (int o = 128; o; o >>= 1) {
        if (tid < o) { r1[tid] += r1[tid + o]; r2[tid] += r2[tid + o];
                       r3[tid] += r3[tid + o]; r4[tid] += r4[tid + o]; }
        __syncthreads();
    }
    if (tid == 0) {
        out[0] = r1[0] / fmaxf(r2[0], 1.0f);
        out[1] = r3[0] / fmaxf(r4[0], 1.0f);
    }
}

// ======================================================================================
extern "C" void kernel_launch(void* const* d_in, const int* in_sizes, int n_in,
                              void* d_out, int out_size, void* d_ws, size_t ws_size,
                              hipStream_t stream) {
    const int*   split      = (const int*)d_in[0];
    const float* zq         = (const float*)d_in[1];
    const int*   targets_vq = (const int*)d_in[2];
    const int*   category   = (const int*)d_in[3];
    const int*   batch_id   = (const int*)d_in[4];
    const void*  mask_raw   = d_in[5];
    const int*   d2b        = (const int*)d_in[6];
    const float* split_emb  = (const float*)d_in[7];
    const float* class_emb  = (const float*)d_in[8];
    const float* vq_proj_w  = (const float*)d_in[9];
    const float* vq_proj_b  = (const float*)d_in[10];
    const float* ln1_s      = (const float*)d_in[11];
    const float* ln1_b      = (const float*)d_in[12];
    const float* qkv_w      = (const float*)d_in[13];
    const float* qkv_b      = (const float*)d_in[14];
    const float* attn_w     = (const float*)d_in[15];
    const float* attn_b     = (const float*)d_in[16];
    const float* ln2_s      = (const float*)d_in[17];
    const float* ln2_b      = (const float*)d_in[18];
    const float* fc1_w      = (const float*)d_in[19];
    const float* fc1_b      = (const float*)d_in[20];
    const float* fc2_w      = (const float*)d_in[21];
    const float* fc2_b      = (const float*)d_in[22];
    const float* lnx_s      = (const float*)d_in[23];
    const float* lnx_b      = (const float*)d_in[24];
    const float* sw         = (const float*)d_in[25];
    const float* sb         = (const float*)d_in[26];
    const float* vq_w       = (const float*)d_in[27];
    const float* vq_b       = (const float*)d_in[28];

    char* ws = (char*)d_ws;
    int* mode   = (int*)ws;
    int* mask_i = (int*)(ws + 256);
    float* sce = (float*)(ws + 256 + 4 * NTOK);
    float* smv = sce + NSPLIT;
    float* vce = smv + NSPLIT;
    float* vmv = vce + NVQ;
    char* p = ws + (1 << 20);
    short* qkvT = (short*)p;  p += (size_t)NL * 768 * CH * 2;
    short* attnT = (short*)p; p += (size_t)NL * CH * CH * 2;
    short* fc1T = (short*)p;  p += (size_t)NL * HIDN * CH * 2;
    short* fc2T = (short*)p;  p += (size_t)NL * CH * HIDN * 2;
    short* vqT = (short*)p;   p += (size_t)HIDN * CH * 2;
    float* x  = (float*)p; p += (size_t)NTOK * CH * 4;
    float* xb = (float*)p; p += (size_t)NTOK * CH * 4;
    __hip_bfloat16* h_bf = (__hip_bfloat16*)p; p += (size_t)NTOK * CH * 2;
    __hip_bfloat16* o_bf = (__hip_bfloat16*)p; p += (size_t)NTOK * CH * 2;
    float* big = (float*)p;   // qkv f32 | fc1-out bf16 | vq logits f32 (time-shared)

    k_detect<<<1, 256, 0, stream>>>((const unsigned short*)mask_raw, mode);
    k_norm_mask<<<NTOK / 256, 256, 0, stream>>>(mask_raw, mode, mask_i);

    k_wt<<<dim3(768 / 64, CH / 64, NL), 256, 0, stream>>>(qkv_w, (__hip_bfloat16*)qkvT, CH, 768);
    k_wt<<<dim3(CH / 64, CH / 64, NL), 256, 0, stream>>>(attn_w, (__hip_bfloat16*)attnT, CH, CH);
    k_wt<<<dim3(HIDN / 64, CH / 64, NL), 256, 0, stream>>>(fc1_w, (__hip_bfloat16*)fc1T, CH, HIDN);
    k_wt<<<dim3(CH / 64, HIDN / 64, NL), 256, 0, stream>>>(fc2_w, (__hip_bfloat16*)fc2T, HIDN, CH);
    k_wt<<<dim3(HIDN / 64, CH / 64, 1), 256, 0, stream>>>(vq_w, (__hip_bfloat16*)vqT, CH, HIDN);

    k_embed<<<NTOK, 256, 0, stream>>>(split, zq, category, batch_id, mask_i,
                                      split_emb, class_emb, vq_proj_w, vq_proj_b, x);
    k_gather_pos<<<NTOK, 256, 0, stream>>>(x, d2b, xb);

    for (int l = 0; l < NL; l++) {
        int d = (l & 1) ? 2 : 1;
        k_layernorm<<<NTOK / 4, 256, 0, stream>>>(xb, ln1_s + l * CH, ln1_b + l * CH, h_bf);
        k_mm<0, 0, 0><<<dim3(768 / 128, NTOK / 128), 256, 0, stream>>>(
            (const short*)h_bf, qkvT + (size_t)l * 768 * CH, qkv_b + l * 768,
            nullptr, big, nullptr, NTOK, 768, CH);
        k_attn<<<dim3(NTOK / PW, NH), 256, 0, stream>>>(big, o_bf, d);
        k_mm<0, 1, 0><<<dim3(CH / 128, NTOK / 128), 256, 0, stream>>>(
            (const short*)o_bf, attnT + (size_t)l * CH * CH, attn_b + l * CH,
            xb, xb, nullptr, NTOK, CH, CH);
        k_layernorm<<<NTOK / 4, 256, 0, stream>>>(xb, ln2_s + l * CH, ln2_b + l * CH, h_bf);
        k_mm<1, 0, 1><<<dim3(HIDN / 128, NTOK / 128), 256, 0, stream>>>(
            (const short*)h_bf, fc1T + (size_t)l * HIDN * CH, fc1_b + l * HIDN,
            nullptr, nullptr, (__hip_bfloat16*)big, NTOK, HIDN, CH);
        k_mm<0, 1, 0><<<dim3(CH / 128, NTOK / 128), 256, 0, stream>>>(
            (const short*)big, fc2T + (size_t)l * CH * HIDN, fc2_b + l * CH,
            xb, xb, nullptr, NTOK, CH, HIDN);
    }

    k_scatter<<<NTOK, 256, 0, stream>>>(xb, d2b, x);
    k_layernorm<<<NTOK / 4, 256, 0, stream>>>(x, lnx_s, lnx_b, h_bf);
    k_split<<<NSPLIT / 4, 256, 0, stream>>>(h_bf, split, mask_i, sw, sb, sce, smv);
    k_mm<0, 0, 0><<<dim3(HIDN / 128, NVQ / 128), 256, 0, stream>>>(
        (const short*)(h_bf + (size_t)NSPLIT * CH), vqT, vq_b,
        nullptr, big, nullptr, NVQ, HIDN, CH);
    k_vq_loss<<<NVQ, 256, 0, stream>>>(big, targets_vq, mask_i, vce, vmv);
    k_reduce<<<1, 256, 0, stream>>>(sce, smv, vce, vmv, (float*)d_out);
}

// Round 3
// 586.127 us; speedup vs baseline: 4.4908x; 1.5683x over previous
//
#include <hip/hip_runtime.h>
#include <hip/hip_bf16.h>
#include <math.h>

#define NSPLIT 4096
#define NVQ    12288
#define NTOK   16384
#define CH     256
#define NH     8
#define DHD    32
#define NL     4
#define PW     256
#define HIDN   1024
#define DVQ    32
#define VQG    4
#define VQS    256

typedef __attribute__((ext_vector_type(8))) short bf16x8;
typedef __attribute__((ext_vector_type(4))) float f32x4;

typedef const __attribute__((address_space(1))) void* gas_ptr;
typedef __attribute__((address_space(3))) void* las_ptr;
#define GLD16(g, s) __builtin_amdgcn_global_load_lds((gas_ptr)(g), (las_ptr)(s), 16, 0, 0)

static __device__ __forceinline__ unsigned pack2bf(float a, float b) {
    __hip_bfloat16 ha = __float2bfloat16(a), hb = __float2bfloat16(b);
    return ((unsigned)*(unsigned short*)&hb << 16) | *(unsigned short*)&ha;
}

// ---------------- mask dtype detection (bool may arrive as i32/u8/bf16/f32) -----------
__global__ void k_detect(const unsigned short* __restrict__ u16, int* __restrict__ mode) {
    __shared__ int c_even, c_odd, c_0100;
    if (threadIdx.x == 0) { c_even = 0; c_odd = 0; c_0100 = 0; }
    __syncthreads();
    int le = 0, lo = 0, l01 = 0;
    for (int i = threadIdx.x; i < 8192; i += blockDim.x) {
        unsigned short v = u16[i];
        if (v == 0x3F80u) { if (i & 1) lo++; else le++; }
        if (v == 0x0100u) l01++;
    }
    atomicAdd(&c_even, le); atomicAdd(&c_odd, lo); atomicAdd(&c_0100, l01);
    __syncthreads();
    if (threadIdx.x == 0) {
        int m;
        if      (c_even > 500) m = 2;
        else if (c_odd  > 500) m = 3;
        else if (c_0100 > 500) m = 1;
        else                   m = 0;
        *mode = m;
    }
}

__global__ void k_norm_mask(const void* __restrict__ raw, const int* __restrict__ mode,
                            int* __restrict__ mi) {
    int i = blockIdx.x * blockDim.x + threadIdx.x;
    if (i >= NTOK) return;
    int m = *mode, v;
    if      (m == 0) v = ((const int*)raw)[i] != 0;
    else if (m == 1) v = ((const unsigned char*)raw)[i] != 0;
    else if (m == 2) v = ((const unsigned short*)raw)[i] != 0;
    else             v = ((const unsigned int*)raw)[i] != 0;
    mi[i] = v;
}

// ---------------- weight transpose + bf16 convert: W[K][N] -> Wt[N][K] -----------------
__global__ void k_wt(const float* __restrict__ W, __hip_bfloat16* __restrict__ Wt,
                     int K, int N) {
    W  += (size_t)blockIdx.z * K * N;
    Wt += (size_t)blockIdx.z * K * N;
    __shared__ float t[64][65];
    int bn = blockIdx.x * 64, bk = blockIdx.y * 64;
    int tid = threadIdx.x;
#pragma unroll
    for (int it = 0; it < 16; ++it) {
        int idx = it * 256 + tid; int r = idx >> 6, c = idx & 63;
        t[r][c] = W[(size_t)(bk + r) * N + bn + c];
    }
    __syncthreads();
#pragma unroll
    for (int it = 0; it < 16; ++it) {
        int idx = it * 256 + tid; int r = idx >> 6, c = idx & 63;
        Wt[(size_t)(bn + r) * K + bk + c] = __float2bfloat16(t[c][r]);
    }
}

// ---------------- embedding -----------------------------------------------------------
__global__ void k_embed(const int* __restrict__ split, const float* __restrict__ zq,
                        const int* __restrict__ category, const int* __restrict__ batch_id,
                        const int* __restrict__ mask_i,
                        const float* __restrict__ split_emb, const float* __restrict__ class_emb,
                        const float* __restrict__ vq_proj_w, const float* __restrict__ vq_proj_b,
                        float* __restrict__ x) {
    int idx = blockIdx.x * 256 + threadIdx.x;
    int i = idx >> 8, c = idx & 255;
    float v;
    if (mask_i[i]) {
        v = class_emb[category[batch_id[i]] * CH + c];
    } else if (i < NSPLIT) {
        v = split_emb[split[i] * CH + c];
    } else {
        const float* z = zq + (size_t)(i - NSPLIT) * DVQ;
        float acc = vq_proj_b[c];
#pragma unroll
        for (int k = 0; k < DVQ; k++) acc += z[k] * vq_proj_w[k * CH + c];
        v = acc;
    }
    x[idx] = v;
}

// ---------------- depth2batch gather + sinusoidal pos emb ------------------------------
__global__ void k_gather_pos(const float* __restrict__ x, const int* __restrict__ d2b,
                             float* __restrict__ xb) {
    int idx = blockIdx.x * 256 + threadIdx.x;
    int j = idx >> 8, c = idx & 255;
    const float kneg = -0.07195578415606394f;  // -ln(10000)/128
    float pe;
    float jf = (float)j;
    if (c < 128) { float f = expf(c * kneg);          pe = sinf(jf * f); }
    else         { float f = expf((c - 128) * kneg);  pe = cosf(jf * f); }
    xb[idx] = x[(size_t)d2b[j] * CH + c] + pe;
}

// ---------------- layernorm: wave per row, bf16 out ------------------------------------
__global__ void k_layernorm(const float* __restrict__ in, const float* __restrict__ s,
                            const float* __restrict__ b, __hip_bfloat16* __restrict__ out) {
    int row = blockIdx.x * 4 + (threadIdx.x >> 6);
    int l = threadIdx.x & 63;
    const float* ip = in + (size_t)row * CH;
    float4 v = *(const float4*)(ip + l * 4);
    float sum = v.x + v.y + v.z + v.w;
    float sq  = v.x * v.x + v.y * v.y + v.z * v.z + v.w * v.w;
#pragma unroll
    for (int o = 32; o; o >>= 1) { sum += __shfl_xor(sum, o); sq += __shfl_xor(sq, o); }
    float mean = sum * (1.0f / CH);
    float var  = sq * (1.0f / CH) - mean * mean;
    float rs = rsqrtf(var + 1e-5f);
    float4 sv = *(const float4*)(s + l * 4);
    float4 bv = *(const float4*)(b + l * 4);
    __hip_bfloat16 h0 = __float2bfloat16((v.x - mean) * rs * sv.x + bv.x);
    __hip_bfloat16 h1 = __float2bfloat16((v.y - mean) * rs * sv.y + bv.y);
    __hip_bfloat16 h2 = __float2bfloat16((v.z - mean) * rs * sv.z + bv.z);
    __hip_bfloat16 h3 = __float2bfloat16((v.w - mean) * rs * sv.w + bv.w);
    ushort4 pk = { *(unsigned short*)&h0, *(unsigned short*)&h1,
                   *(unsigned short*)&h2, *(unsigned short*)&h3 };
    *(ushort4*)((unsigned short*)out + (size_t)row * CH + l * 4) = pk;
}

// ---------------- MFMA bf16 GEMM: out = act(A @ Bt^T + bias) [+res] --------------------
template <int GELU, int RES, int OBF>
__global__ __launch_bounds__(256, 2) void k_mm(
    const short* __restrict__ A, const short* __restrict__ Bt,
    const float* __restrict__ bias, const float* __restrict__ res,
    float* __restrict__ outF, __hip_bfloat16* __restrict__ outB,
    int M, int N, int K) {
    __shared__ short As[128 * 32];
    __shared__ short Bs[128 * 32];
    const int tid = threadIdx.x;
    const int w = tid >> 6, l = tid & 63;
    const int bm = blockIdx.y * 128, bn = blockIdx.x * 128;
    const int wr = w >> 1, wc = w & 1;
    const int q = l >> 4, rA = l & 15;
    const int srow = w * 16 + (l >> 2);
    const int sx = ((l & 3) ^ ((l >> 2) & 3)) * 8;
    const int fx = (q ^ (rA & 3)) * 8;

    const short* gA0 = A + (size_t)(bm + srow) * K + sx;
    const short* gA1 = A + (size_t)(bm + srow + 64) * K + sx;
    const short* gB0 = Bt + (size_t)(bn + srow) * K + sx;
    const short* gB1 = Bt + (size_t)(bn + srow + 64) * K + sx;
    short* lA0 = As + w * 16 * 32;
    short* lA1 = As + (64 + w * 16) * 32;
    short* lB0 = Bs + w * 16 * 32;
    short* lB1 = Bs + (64 + w * 16) * 32;

    f32x4 acc[4][4] = {};

    for (int k0 = 0; k0 < K; k0 += 32) {
        GLD16(gA0 + k0, lA0);
        GLD16(gA1 + k0, lA1);
        GLD16(gB0 + k0, lB0);
        GLD16(gB1 + k0, lB1);
        __syncthreads();
        bf16x8 a[4], b[4];
#pragma unroll
        for (int m = 0; m < 4; m++)
            a[m] = *(const bf16x8*)(As + (wr * 64 + m * 16 + rA) * 32 + fx);
#pragma unroll
        for (int n = 0; n < 4; n++)
            b[n] = *(const bf16x8*)(Bs + (wc * 64 + n * 16 + rA) * 32 + fx);
#pragma unroll
        for (int m = 0; m < 4; m++)
#pragma unroll
            for (int n = 0; n < 4; n++)
                acc[m][n] = __builtin_amdgcn_mfma_f32_16x16x32_bf16(a[m], b[n], acc[m][n], 0, 0, 0);
        __syncthreads();
    }

#pragma unroll
    for (int m = 0; m < 4; m++) {
        int row0 = bm + wr * 64 + m * 16 + q * 4;
#pragma unroll
        for (int n = 0; n < 4; n++) {
            int col = bn + wc * 64 + n * 16 + rA;
            float bv = bias[col];
#pragma unroll
            for (int r2 = 0; r2 < 4; r2++) {
                int row = row0 + r2;
                float v = acc[m][n][r2] + bv;
                if (GELU) {
                    float t = tanhf(0.7978845608028654f * (v + 0.044715f * v * v * v));
                    v = 0.5f * v * (1.0f + t);
                }
                size_t oi = (size_t)row * N + col;
                if (RES) v += res[oi];
                if (OBF) outB[oi] = __float2bfloat16(v);
                else     outF[oi] = v;
            }
        }
    }
}

// ---------------- MFMA fused window attention ------------------------------------------
// qkv bf16 [NTOK][768]; out bf16 [NTOK][256]. Block = (window, head), 4 waves x 64 q-rows.
// S^T = K @ Q^T (swapped) so softmax stats are per q-col (lane&15): 2-shfl reduce.
__global__ __launch_bounds__(256) void k_attn_mfma(const short* __restrict__ qkv,
                                                   short* __restrict__ o, int dil) {
    __shared__ short Vt[DHD * PW];          // [d][kv], chunk-swizzled: 16KB
    __shared__ short Pl[4][64 * 64];        // per-wave P[q][kv-chunk], swizzled: 32KB
    const int wid = blockIdx.x, h = blockIdx.y;
    const int tid = threadIdx.x;
    const int w = tid >> 6, l = tid & 63;
    const int g = l >> 4, c = l & 15;
    const int tbase = (wid / dil) * (PW * dil) + (wid % dil);

    // ---- stage V transposed: thread p handles token p (32 bf16 -> 32 scalar LDS writes)
    {
        const int p = tid;
        const short* src = qkv + (size_t)(tbase + p * dil) * 768 + 2 * CH + h * DHD;
        bf16x8 v0 = *(const bf16x8*)(src);
        bf16x8 v1 = *(const bf16x8*)(src + 8);
        bf16x8 v2 = *(const bf16x8*)(src + 16);
        bf16x8 v3 = *(const bf16x8*)(src + 24);
        const int pc = p >> 3, po = p & 7;
#pragma unroll
        for (int d = 0; d < 8; d++)  Vt[(d)      * PW + ((pc ^ d)        << 3) + po] = v0[d];
#pragma unroll
        for (int d = 0; d < 8; d++)  Vt[(d + 8)  * PW + ((pc ^ d)        << 3) + po] = v1[d];
#pragma unroll
        for (int d = 0; d < 8; d++)  Vt[(d + 16) * PW + ((pc ^ d)        << 3) + po] = v2[d];
#pragma unroll
        for (int d = 0; d < 8; d++)  Vt[(d + 24) * PW + ((pc ^ d)        << 3) + po] = v3[d];
    }

    // ---- Q fragments (B-operand): col=q=lane&15, k=d=g*8..+7 (loaded once)
    bf16x8 qf[4];
#pragma unroll
    for (int qt = 0; qt < 4; qt++) {
        int qrow = w * 64 + qt * 16 + c;
        qf[qt] = *(const bf16x8*)(qkv + (size_t)(tbase + qrow * dil) * 768 + h * DHD + g * 8);
    }

    f32x4 acco[4][2] = {};                  // O^... O C-layout: [q-tile][d-tile]
    float m_s[4] = {-1e30f, -1e30f, -1e30f, -1e30f};
    float l_s[4] = {0.f, 0.f, 0.f, 0.f};
    const float scale = 0.17677669529663687f;  // 1/sqrt(32)

    __syncthreads();                        // Vt ready

#pragma unroll
    for (int ch = 0; ch < 4; ch++) {
        // ---- K fragments (A-operand): row=kv=lane&15(+16*kvt), k=d=g*8..+7
        bf16x8 kf[4];
#pragma unroll
        for (int kvt = 0; kvt < 4; kvt++) {
            int kv = ch * 64 + kvt * 16 + c;
            kf[kvt] = *(const bf16x8*)(qkv + (size_t)(tbase + kv * dil) * 768 + CH + h * DHD + g * 8);
        }
        // ---- S^T chunk: [kv 64][q 64]
        f32x4 accs[4][4] = {};              // [kvt][qt]
#pragma unroll
        for (int kvt = 0; kvt < 4; kvt++)
#pragma unroll
            for (int qt = 0; qt < 4; qt++)
                accs[kvt][qt] = __builtin_amdgcn_mfma_f32_16x16x32_bf16(kf[kvt], qf[qt], accs[kvt][qt], 0, 0, 0);

        // ---- online softmax per q-col (lane&15)
        float fb[4];
#pragma unroll
        for (int qt = 0; qt < 4; qt++) {
            float mx = -1e30f;
#pragma unroll
            for (int kvt = 0; kvt < 4; kvt++) {
                mx = fmaxf(mx, fmaxf(fmaxf(accs[kvt][qt][0], accs[kvt][qt][1]),
                                     fmaxf(accs[kvt][qt][2], accs[kvt][qt][3])));
            }
            mx = fmaxf(mx, __shfl_xor(mx, 16));
            mx = fmaxf(mx, __shfl_xor(mx, 32));
            float mnew = fmaxf(m_s[qt], mx * scale);
            fb[qt] = __expf(m_s[qt] - mnew);
            m_s[qt] = mnew;
        }
        // ---- rescale O (O rows q=(g*4+r): fetch f from lane c'=g*4+r)
#pragma unroll
        for (int mt = 0; mt < 4; mt++)
#pragma unroll
            for (int r = 0; r < 4; r++) {
                float fo = __shfl(fb[mt], g * 4 + r);
                acco[mt][0][r] *= fo;
                acco[mt][1][r] *= fo;
            }
        // ---- P = exp(S*scale - m), write to per-wave LDS [q][kv] (b64, swizzled)
        float rsum[4] = {0.f, 0.f, 0.f, 0.f};
#pragma unroll
        for (int kvt = 0; kvt < 4; kvt++) {
            const int cchunk = kvt * 2 + (g >> 1);
            const int koff = (g & 1) << 2;
#pragma unroll
            for (int qt = 0; qt < 4; qt++) {
                float p0 = __expf(accs[kvt][qt][0] * scale - m_s[qt]);
                float p1 = __expf(accs[kvt][qt][1] * scale - m_s[qt]);
                float p2 = __expf(accs[kvt][qt][2] * scale - m_s[qt]);
                float p3 = __expf(accs[kvt][qt][3] * scale - m_s[qt]);
                rsum[qt] += (p0 + p1) + (p2 + p3);
                int qq = qt * 16 + c;
                int phys = cchunk ^ (qq & 7);
                uint2 pk; pk.x = pack2bf(p0, p1); pk.y = pack2bf(p2, p3);
                *(uint2*)(&Pl[w][qq * 64 + phys * 8 + koff]) = pk;
            }
        }
#pragma unroll
        for (int qt = 0; qt < 4; qt++) {
            float s = rsum[qt];
            s += __shfl_xor(s, 16);
            s += __shfl_xor(s, 32);
            l_s[qt] = l_s[qt] * fb[qt] + s;
        }
        // ---- PV: O[q][d] += P[q][kv] @ V[kv][d]  (A from Pl, B from Vt)
#pragma unroll
        for (int ks = 0; ks < 2; ks++) {
            bf16x8 pa[4];
#pragma unroll
            for (int mt = 0; mt < 4; mt++) {
                int qq = mt * 16 + c;
                int phys = (ks * 4 + g) ^ (qq & 7);
                pa[mt] = *(const bf16x8*)(&Pl[w][qq * 64 + phys * 8]);
            }
#pragma unroll
            for (int nt = 0; nt < 2; nt++) {
                int d = nt * 16 + c;
                int kvabs = ch * 64 + ks * 32 + g * 8;
                int phys = (kvabs >> 3) ^ (d & 7);
                bf16x8 vb = *(const bf16x8*)(&Vt[d * PW + phys * 8]);
#pragma unroll
                for (int mt = 0; mt < 4; mt++)
                    acco[mt][nt] = __builtin_amdgcn_mfma_f32_16x16x32_bf16(pa[mt], vb, acco[mt][nt], 0, 0, 0);
            }
        }
    }

    // ---- epilogue: O /= l, write bf16 scalars
#pragma unroll
    for (int mt = 0; mt < 4; mt++) {
        float linv_own = 1.0f / l_s[mt];
#pragma unroll
        for (int r = 0; r < 4; r++) {
            float linv = __shfl(linv_own, g * 4 + r);
            int qrow = w * 64 + mt * 16 + g * 4 + r;
            size_t trow = (size_t)(tbase + qrow * dil) * CH + h * DHD;
#pragma unroll
            for (int nt = 0; nt < 2; nt++) {
                __hip_bfloat16 hv = __float2bfloat16(acco[mt][nt][r] * linv);
                o[trow + nt * 16 + c] = *(short*)&hv;
            }
        }
    }
}

// ---------------- batch2depth scatter --------------------------------------------------
__global__ void k_scatter(const float* __restrict__ xb, const int* __restrict__ d2b,
                          float* __restrict__ x) {
    int j = blockIdx.x, c = threadIdx.x;
    x[(size_t)d2b[j] * CH + c] = xb[(size_t)j * CH + c];
}

// ---------------- split head + masked CE (wave per token, partials) --------------------
__global__ void k_split(const __hip_bfloat16* __restrict__ xln, const int* __restrict__ split,
                        const int* __restrict__ mask_i, const float* __restrict__ sw,
                        const float* __restrict__ sb, float* __restrict__ sce,
                        float* __restrict__ smv) {
    int tok = blockIdx.x * 4 + (threadIdx.x >> 6);
    int l = threadIdx.x & 63;
    float a0 = 0.f, a1 = 0.f;
#pragma unroll
    for (int jj = 0; jj < 4; jj++) {
        int c = l + 64 * jj;
        float v = __bfloat162float(xln[(size_t)tok * CH + c]);
        a0 += v * sw[2 * c + 0];
        a1 += v * sw[2 * c + 1];
    }
#pragma unroll
    for (int o = 32; o; o >>= 1) { a0 += __shfl_xor(a0, o); a1 += __shfl_xor(a1, o); }
    if (l == 0) {
        float l0 = a0 + sb[0], l1 = a1 + sb[1];
        float mx = fmaxf(l0, l1);
        float lse = mx + logf(__expf(l0 - mx) + __expf(l1 - mx));
        float ce = lse - (split[tok] ? l1 : l0);
        float ms = (float)mask_i[tok];
        sce[tok] = ce * ms;
        smv[tok] = ms;
    }
}

// ---------------- vq grouped CE (wave per group, partials) -----------------------------
__global__ void k_vq_loss(const float* __restrict__ vl, const int* __restrict__ targets,
                          const int* __restrict__ mask_i, float* __restrict__ vce,
                          float* __restrict__ vmv) {
    int i = blockIdx.x;
    int wv = threadIdx.x >> 6;
    int l = threadIdx.x & 63;
    const float* row = vl + (size_t)i * (VQG * VQS) + wv * VQS;
    float4 v = *(const float4*)(row + l * 4);
    float mx = fmaxf(fmaxf(v.x, v.y), fmaxf(v.z, v.w));
#pragma unroll
    for (int o = 32; o; o >>= 1) mx = fmaxf(mx, __shfl_xor(mx, o));
    float s = __expf(v.x - mx) + __expf(v.y - mx) + __expf(v.z - mx) + __expf(v.w - mx);
#pragma unroll
    for (int o = 32; o; o >>= 1) s += __shfl_xor(s, o);
    __shared__ float ce[VQG];
    if (l == 0) ce[wv] = (mx + logf(s)) - row[targets[i * VQG + wv]];
    __syncthreads();
    if (threadIdx.x == 0) {
        float mv = (float)mask_i[NSPLIT + i];
        vce[i] = (ce[0] + ce[1] + ce[2] + ce[3]) * 0.25f * mv;
        vmv[i] = mv;
    }
}

// ---------------- final reduction ------------------------------------------------------
__global__ void k_reduce(const float* __restrict__ sce, const float* __restrict__ smv,
                         const float* __restrict__ vce, const float* __restrict__ vmv,
                         float* __restrict__ out) {
    int tid = threadIdx.x;
    float s1 = 0, s2 = 0, s3 = 0, s4 = 0;
    for (int i = tid; i < NSPLIT; i += 256) { s1 += sce[i]; s2 += smv[i]; }
    for (int i = tid; i < NVQ; i += 256)    { s3 += vce[i]; s4 += vmv[i]; }
    __shared__ float r1[256], r2[256], r3[256], r4[256];
    r1[tid] = s1; r2[tid] = s2; r3[tid] = s3; r4[tid] = s4;
    __syncthreads();
    for (int o = 128; o; o >>= 1) {
        if (tid < o) { r1[tid] += r1[tid + o]; r2[tid] += r2[tid + o];
                       r3[tid] += r3[tid + o]; r4[tid] += r4[tid + o]; }
        __syncthreads();
    }
    if (tid == 0) {
        out[0] = r1[0] / fmaxf(r2[0], 1.0f);
        out[1] = r3[0] / fmaxf(r4[0], 1.0f);
    }
}

// ======================================================================================
extern "C" void kernel_launch(void* const* d_in, const int* in_sizes, int n_in,
                              void* d_out, int out_size, void* d_ws, size_t ws_size,
                              hipStream_t stream) {
    const int*   split      = (const int*)d_in[0];
    const float* zq         = (const float*)d_in[1];
    const int*   targets_vq = (const int*)d_in[2];
    const int*   category   = (const int*)d_in[3];
    const int*   batch_id   = (const int*)d_in[4];
    const void*  mask_raw   = d_in[5];
    const int*   d2b        = (const int*)d_in[6];
    const float* split_emb  = (const float*)d_in[7];
    const float* class_emb  = (const float*)d_in[8];
    const float* vq_proj_w  = (const float*)d_in[9];
    const float* vq_proj_b  = (const float*)d_in[10];
    const float* ln1_s      = (const float*)d_in[11];
    const float* ln1_b      = (const float*)d_in[12];
    const float* qkv_w      = (const float*)d_in[13];
    const float* qkv_b      = (const float*)d_in[14];
    const float* attn_w     = (const float*)d_in[15];
    const float* attn_b     = (const float*)d_in[16];
    const float* ln2_s      = (const float*)d_in[17];
    const float* ln2_b      = (const float*)d_in[18];
    const float* fc1_w      = (const float*)d_in[19];
    const float* fc1_b      = (const float*)d_in[20];
    const float* fc2_w      = (const float*)d_in[21];
    const float* fc2_b      = (const float*)d_in[22];
    const float* lnx_s      = (const float*)d_in[23];
    const float* lnx_b      = (const float*)d_in[24];
    const float* sw         = (const float*)d_in[25];
    const float* sb         = (const float*)d_in[26];
    const float* vq_w       = (const float*)d_in[27];
    const float* vq_b       = (const float*)d_in[28];

    char* ws = (char*)d_ws;
    int* mode   = (int*)ws;
    int* mask_i = (int*)(ws + 256);
    float* sce = (float*)(ws + 256 + 4 * NTOK);
    float* smv = sce + NSPLIT;
    float* vce = smv + NSPLIT;
    float* vmv = vce + NVQ;
    char* p = ws + (1 << 20);
    short* qkvT = (short*)p;  p += (size_t)NL * 768 * CH * 2;
    short* attnT = (short*)p; p += (size_t)NL * CH * CH * 2;
    short* fc1T = (short*)p;  p += (size_t)NL * HIDN * CH * 2;
    short* fc2T = (short*)p;  p += (size_t)NL * CH * HIDN * 2;
    short* vqT = (short*)p;   p += (size_t)HIDN * CH * 2;
    float* x  = (float*)p; p += (size_t)NTOK * CH * 4;
    float* xb = (float*)p; p += (size_t)NTOK * CH * 4;
    __hip_bfloat16* h_bf = (__hip_bfloat16*)p; p += (size_t)NTOK * CH * 2;
    __hip_bfloat16* o_bf = (__hip_bfloat16*)p; p += (size_t)NTOK * CH * 2;
    float* big = (float*)p;   // qkv bf16 | fc1-out bf16 | vq logits f32 (time-shared)

    k_detect<<<1, 256, 0, stream>>>((const unsigned short*)mask_raw, mode);
    k_norm_mask<<<NTOK / 256, 256, 0, stream>>>(mask_raw, mode, mask_i);

    k_wt<<<dim3(768 / 64, CH / 64, NL), 256, 0, stream>>>(qkv_w, (__hip_bfloat16*)qkvT, CH, 768);
    k_wt<<<dim3(CH / 64, CH / 64, NL), 256, 0, stream>>>(attn_w, (__hip_bfloat16*)attnT, CH, CH);
    k_wt<<<dim3(HIDN / 64, CH / 64, NL), 256, 0, stream>>>(fc1_w, (__hip_bfloat16*)fc1T, CH, HIDN);
    k_wt<<<dim3(CH / 64, HIDN / 64, NL), 256, 0, stream>>>(fc2_w, (__hip_bfloat16*)fc2T, HIDN, CH);
    k_wt<<<dim3(HIDN / 64, CH / 64, 1), 256, 0, stream>>>(vq_w, (__hip_bfloat16*)vqT, CH, HIDN);

    k_embed<<<NTOK, 256, 0, stream>>>(split, zq, category, batch_id, mask_i,
                                      split_emb, class_emb, vq_proj_w, vq_proj_b, x);
    k_gather_pos<<<NTOK, 256, 0, stream>>>(x, d2b, xb);

    for (int l = 0; l < NL; l++) {
        int d = (l & 1) ? 2 : 1;
        k_layernorm<<<NTOK / 4, 256, 0, stream>>>(xb, ln1_s + l * CH, ln1_b + l * CH, h_bf);
        k_mm<0, 0, 1><<<dim3(768 / 128, NTOK / 128), 256, 0, stream>>>(
            (const short*)h_bf, qkvT + (size_t)l * 768 * CH, qkv_b + l * 768,
            nullptr, nullptr, (__hip_bfloat16*)big, NTOK, 768, CH);
        k_attn_mfma<<<dim3(NTOK / PW, NH), 256, 0, stream>>>(
            (const short*)big, (short*)o_bf, d);
        k_mm<0, 1, 0><<<dim3(CH / 128, NTOK / 128), 256, 0, stream>>>(
            (const short*)o_bf, attnT + (size_t)l * CH * CH, attn_b + l * CH,
            xb, xb, nullptr, NTOK, CH, CH);
        k_layernorm<<<NTOK / 4, 256, 0, stream>>>(xb, ln2_s + l * CH, ln2_b + l * CH, h_bf);
        k_mm<1, 0, 1><<<dim3(HIDN / 128, NTOK / 128), 256, 0, stream>>>(
            (const short*)h_bf, fc1T + (size_t)l * HIDN * CH, fc1_b + l * HIDN,
            nullptr, nullptr, (__hip_bfloat16*)big, NTOK, HIDN, CH);
        k_mm<0, 1, 0><<<dim3(CH / 128, NTOK / 128), 256, 0, stream>>>(
            (const short*)big, fc2T + (size_t)l * CH * HIDN, fc2_b + l * CH,
            xb, xb, nullptr, NTOK, CH, HIDN);
    }

    k_scatter<<<NTOK, 256, 0, stream>>>(xb, d2b, x);
    k_layernorm<<<NTOK / 4, 256, 0, stream>>>(x, lnx_s, lnx_b, h_bf);
    k_split<<<NSPLIT / 4, 256, 0, stream>>>(h_bf, split, mask_i, sw, sb, sce, smv);
    k_mm<0, 0, 0><<<dim3(HIDN / 128, NVQ / 128), 256, 0, stream>>>(
        (const short*)(h_bf + (size_t)NSPLIT * CH), vqT, vq_b,
        nullptr, big, nullptr, NVQ, HIDN, CH);
    k_vq_loss<<<NVQ, 256, 0, stream>>>(big, targets_vq, mask_i, vce, vmv);
    k_reduce<<<1, 256, 0, stream>>>(sce, smv, vce, vmv, (float*)d_out);
}